// Round 2
// baseline (45.036 us; speedup 1.0000x reference)
//
#include <hip/hip_runtime.h>
#include <float.h>

#define BB 32
#define CC 128
#define HH 64
#define WW 64

// One wave per (b, lmi, channel). Block = 4 waves = 4 consecutive channels.
// Grid = B * 8 * (C/4) = 32*8*32 = 8192 blocks.
__global__ __launch_bounds__(256) void roipool_kernel(
    const float* __restrict__ x,   // [B,C,64,64]
    const float* __restrict__ lm,  // [B,16]
    float* __restrict__ out)       // [B,C,32,16]
{
    int blk = blockIdx.x;
    int cg  = blk & 31;          // channel group (4 channels each)
    int lmi = (blk >> 5) & 7;    // landmark 0..7
    int b   = blk >> 8;          // batch

    int wave = threadIdx.x >> 6;
    int lane = threadIdx.x & 63;
    int c = cg * 4 + wave;

    __shared__ float sdata[4][8][65];   // stride-65 kills stage-2 bank conflicts

    float x0 = lm[b * 16 + 2 * lmi];
    float y0 = lm[b * 16 + 2 * lmi + 1];
    bool visible = (x0 > 0.0f) || (y0 > 0.0f);

    // torchvision column-swap semantics:
    // rois=(b,x1,x2,y1,y2) consumed as (b,start_w,start_h,end_w,end_h)
    int fx = (int)floorf(x0 * 0.25f);
    int fy = (int)floorf(y0 * 0.25f);
    // start_w = fx-7, start_h = fx, end_w = fy-7, end_h = fy
    int roi = max(fy - fx + 1, 1);          // roi_w == roi_h
    float bin = (float)roi * 0.125f;        // exact /8 in fp32

    // clipped column window; width <= 64 (proven: fx in [-5,59], roi <= 65)
    int w0 = max(fx - 7, 0);
    int w1 = min(fx - 7 + roi, WW);         // ceil(8*bin) == roi
    int width = w1 - w0;                    // may be <= 0 (all-empty)

    const float* __restrict__ xp = x + (size_t)(b * CC + c) * (HH * WW);

    // ---- Stage 1: per-column max within each of the 8 row bins ----
    // Row-bin bounds are wave-uniform; loads are 64-wide coalesced.
    #pragma unroll
    for (int i = 0; i < 8; ++i) {
        int hsi = min(max((int)floorf((float)i * bin) + fx, 0), HH);
        int hei = min(max((int)ceilf((float)(i + 1) * bin) + fx, 0), HH);
        float m = -FLT_MAX;
        if (lane < width) {
            for (int h = hsi; h < hei; ++h)
                m = fmaxf(m, xp[h * WW + w0 + lane]);
        }
        sdata[wave][i][lane] = m;
    }
    __syncthreads();   // uniform per block (all waves share b,lmi -> same trip counts)

    // ---- Stage 2: pool columns; lane <-> (i,j) output cell ----
    int i = lane >> 3;
    int j = lane & 7;
    // recompute bounds (closed form; avoids runtime-indexed register arrays)
    int hsi = min(max((int)floorf((float)i * bin) + fx, 0), HH);
    int hei = min(max((int)ceilf((float)(i + 1) * bin) + fx, 0), HH);
    int wsj = min(max((int)floorf((float)j * bin) + fx - 7, 0), WW);
    int wej = min(max((int)ceilf((float)(j + 1) * bin) + fx - 7, 0), WW);
    bool empty = (hei <= hsi) || (wej <= wsj);

    float m = -FLT_MAX;
    for (int w = wsj; w < wej; ++w)         // wsj >= w0, wej <= w1 (proven)
        m = fmaxf(m, sdata[wave][i][w - w0]);

    float res = (empty || !visible) ? 0.0f : m;

    int orow = 8 * (lmi >> 1) + i;
    int ocol = 8 * (lmi & 1) + j;
    out[(((size_t)b * CC + c) * 32 + orow) * 16 + ocol] = res;
}

extern "C" void kernel_launch(void* const* d_in, const int* in_sizes, int n_in,
                              void* d_out, int out_size, void* d_ws, size_t ws_size,
                              hipStream_t stream) {
    const float* x  = (const float*)d_in[0];
    const float* lm = (const float*)d_in[1];
    float* out = (float*)d_out;

    int blocks = BB * 8 * (CC / 4);   // 8192
    roipool_kernel<<<blocks, 256, 0, stream>>>(x, lm, out);
}